// Round 18
// baseline (168.740 us; speedup 1.0000x reference)
//
#include <hip/hip_runtime.h>
#include <stdint.h>

typedef __bf16 bf16x8 __attribute__((ext_vector_type(8)));
typedef float f32x4 __attribute__((ext_vector_type(4)));

// ---------- bf16 helpers ----------
__device__ inline float bf2f(uint16_t u) {
    uint32_t x = ((uint32_t)u) << 16;
    float f;
    __builtin_memcpy(&f, &x, 4);
    return f;
}
__device__ inline uint16_t f2bf(float f) {
    uint32_t x;
    __builtin_memcpy(&x, &f, 4);
    uint32_t r = (x + 0x7FFFu + ((x >> 16) & 1u)) >> 16;
    return (uint16_t)r;
}

// ---------------------------------------------------------------------------
// Merged small weight prep (one launch). Runs BEFORE k_front (conv1 reads wA1c).
// ---------------------------------------------------------------------------
__global__ __launch_bounds__(256) void k_prep_small(const float* __restrict__ W2,
                                                    const float* __restrict__ W1,
                                                    const float* __restrict__ Wa,
                                                    uint16_t* __restrict__ wA,
                                                    uint16_t* __restrict__ wA1c,
                                                    uint16_t* __restrict__ waP) {
    int bid = blockIdx.x;
    int tid = threadIdx.x;
    if (bid < 72) {
        int j = bid * 256 + tid;
        if (j >= 18432) return;
        int t = j >> 11, rem = j & 2047, oc = rem >> 5, ic = rem & 31;
        int dy = t / 3, dx = t - dy * 3;
        wA[j] = f2bf(W2[(oc * 32 + ic) * 9 + dy * 3 + dx]);
    } else if (bid < 84) {
        int j = (bid - 72) * 256 + tid;
        if (j >= 3072) return;
        int dy = j >> 10, rem = j & 1023, oc = rem >> 5, k = rem & 31;
        int dx = k >> 2, ic = k & 3;
        uint16_t v = 0;
        if (dx < 3 && ic < 3) v = f2bf(W1[((oc * 3 + ic) * 3 + dy) * 3 + dx]);
        wA1c[j] = v;
    } else {
        int j = (bid - 84) * 256 + tid;
        if (j >= 4096) return;
        int chunk = j >> 10, ks = (j >> 9) & 1, tl = (j >> 5) & 15, ch = j & 31;
        int t = chunk * 16 + tl;
        int cg = ks * 32 + ch;
        waP[j] = (t < 49) ? f2bf(Wa[cg * 49 + t]) : (uint16_t)0;
    }
}

// ---------------------------------------------------------------------------
// k_front: handcrafted (blocks 0..767) + conv1 MFMA (blocks 768..2815).
// conv1 tile = 64x32 conv outputs (32x16 pooled), 8 tiles/image, 4-phase
// epilogue (s_out 8 KB). Grid MUST be 768 + 8*256 = 2816 blocks.
// ---------------------------------------------------------------------------
__global__ __launch_bounds__(256) void k_front(const float* __restrict__ img,
                                               const uint16_t* __restrict__ wA1c,
                                               const float* __restrict__ b1,
                                               uint16_t* __restrict__ pooled1,
                                               float* __restrict__ f) {
    __shared__ __align__(16) uint8_t smem[26144];
    const int bid = blockIdx.x;
    const int tid = threadIdx.x;

    if (bid < 768) {
        // ---------------- handcrafted ----------------
        int c = bid >> 8, b = bid & 255;
        const float* src = img + (((size_t)(b * 3 + c)) << 14);
        uint8_t* u8 = smem;  // [128 rows][stride 132] = 16896 B
        float sum = 0.f, sumsq = 0.f;
        for (int it = 0; it < 16; ++it) {
            int p4 = (it << 10) + (tid << 2);
            float4 v = *(const float4*)&src[p4];
            float f0 = floorf(v.x * 255.f), f1 = floorf(v.y * 255.f);
            float f2 = floorf(v.z * 255.f), f3 = floorf(v.w * 255.f);
            uint32_t pk = (uint32_t)(int)f0 | ((uint32_t)(int)f1 << 8) |
                          ((uint32_t)(int)f2 << 16) | ((uint32_t)(int)f3 << 24);
            int r = p4 >> 7, cc = p4 & 127;
            *(uint32_t*)(u8 + r * 132 + cc) = pk;
            sum += f0 + f1 + f2 + f3;
            sumsq += f0 * f0 + f1 * f1 + f2 * f2 + f3 * f3;
        }
        __syncthreads();
        {
            int r = tid >> 1;
            int c0 = (tid & 1) << 6;
            int rm = (r == 0) ? 1 : r - 1, rp = (r == 127) ? 126 : r + 1;
            const uint8_t* Rt = u8 + rm * 132;
            const uint8_t* Rc = u8 + r * 132;
            const uint8_t* Rb = u8 + rp * 132;
            uint32_t wt = *(const uint32_t*)(Rt + c0);
            uint32_t wm = *(const uint32_t*)(Rc + c0);
            uint32_t wb = *(const uint32_t*)(Rb + c0);
            int lt, lm, lb;  // byte at col cb-1
            if (c0 == 0) {   // col -1 -> reflect-101 -> col 1
                lt = (wt >> 8) & 255; lm = (wm >> 8) & 255; lb = (wb >> 8) & 255;
            } else {
                lt = Rt[63]; lm = Rc[63]; lb = Rb[63];
            }
            float esum = 0.f;
            for (int ch = 0; ch < 16; ++ch) {
                int cb = c0 + (ch << 2);
                bool hn = (cb + 4) < 128;
                uint32_t nt = 0, nm = 0, nb = 0;
                if (hn) {
                    nt = *(const uint32_t*)(Rt + cb + 4);
                    nm = *(const uint32_t*)(Rc + cb + 4);
                    nb = *(const uint32_t*)(Rb + cb + 4);
                }
                int t[6], m[6], bo[6];
                t[0] = lt; m[0] = lm; bo[0] = lb;
#pragma unroll
                for (int i = 0; i < 4; ++i) {
                    t[i + 1] = (wt >> (8 * i)) & 255;
                    m[i + 1] = (wm >> (8 * i)) & 255;
                    bo[i + 1] = (wb >> (8 * i)) & 255;
                }
                t[5] = hn ? (int)(nt & 255) : (int)((wt >> 16) & 255);
                m[5] = hn ? (int)(nm & 255) : (int)((wm >> 16) & 255);
                bo[5] = hn ? (int)(nb & 255) : (int)((wb >> 16) & 255);
#pragma unroll
                for (int i = 0; i < 4; ++i) {
                    int gx = (t[i + 2] - t[i]) + 2 * (m[i + 2] - m[i]) + (bo[i + 2] - bo[i]);
                    int gy = (bo[i] + 2 * bo[i + 1] + bo[i + 2]) - (t[i] + 2 * t[i + 1] + t[i + 2]);
                    esum += sqrtf((float)(gx * gx + gy * gy));
                }
                lt = t[4]; lm = m[4]; lb = bo[4];
                wt = nt; wm = nm; wb = nb;
            }
            for (int off = 32; off; off >>= 1) {
                sum += __shfl_down(sum, off);
                sumsq += __shfl_down(sumsq, off);
                esum += __shfl_down(esum, off);
            }
            __syncthreads();
            float* scratch = (float*)smem;
            int w = tid >> 6;
            if ((tid & 63) == 0) {
                scratch[w * 3 + 0] = sum;
                scratch[w * 3 + 1] = sumsq;
                scratch[w * 3 + 2] = esum;
            }
            __syncthreads();
            if (tid == 0) {
                float S = 0.f, Q = 0.f, E = 0.f;
                for (int i = 0; i < 4; ++i) {
                    S += scratch[i * 3 + 0];
                    Q += scratch[i * 3 + 1];
                    E += scratch[i * 3 + 2];
                }
                const float inv = 1.0f / 16384.0f;
                float mean = S * inv;
                float var = Q * inv - mean * mean;
                f[b * 16 + c] = E * inv;
                f[b * 16 + 3 + c] = mean;
                f[b * 16 + 6 + c] = sqrtf(fmaxf(var, 0.f));
            }
        }
        return;
    }

    // ---------------- conv1 via MFMA (64x32 conv tile, 4-phase store) -------
    {
        uint16_t* s_out = (uint16_t*)smem;            // 8192 B: [8 rows][16 px][32 oc]
        uint16_t* s_nhwc = (uint16_t*)(smem + 8192);  // 17952 B: [66x34 px][4 ic]
        const int j0 = bid - 768;
        const int tile = j0 & 7;
        const int b = j0 >> 3;
        const int ty = tile >> 2, tx = tile & 3;      // ty 0..1, tx 0..3
        const int Y0 = ty * 64, X0 = tx * 32;

        for (int j = tid; j < 2244; j += 256) {       // 66 x 34 px
            int r = j / 34, sc = j - r * 34;
            int gy = Y0 - 1 + r, gx = X0 - 1 + sc;
            uint16_t d[4] = {0, 0, 0, 0};
            if ((unsigned)gy < 128u && (unsigned)gx < 128u) {
                size_t base = (((size_t)b * 3) << 14) + (gy << 7) + gx;
#pragma unroll
                for (int ic = 0; ic < 3; ++ic) d[ic] = f2bf(img[base + ((size_t)ic << 14)]);
            }
            *(uint2*)&s_nhwc[j * 4] = *(uint2*)d;
        }

        const int wv = tid >> 6, lane = tid & 63;
        const int rowl = lane & 15, kg = lane >> 4;

        bf16x8 afr[3][2];
#pragma unroll
        for (int dy = 0; dy < 3; ++dy)
#pragma unroll
            for (int g = 0; g < 2; ++g)
                afr[dy][g] = *(const bf16x8*)(wA1c + dy * 1024 + (g * 16 + rowl) * 32 + kg * 8);
        float bias[2][4];
#pragma unroll
        for (int g = 0; g < 2; ++g)
#pragma unroll
            for (int r = 0; r < 4; ++r)
                bias[g][r] = b1[g * 16 + kg * 4 + r];

        __syncthreads();

#pragma unroll
        for (int p = 0; p < 4; ++p) {
#pragma unroll
            for (int pl = 0; pl < 2; ++pl) {
                const int prow_l = pl * 4 + wv;       // 0..7 within phase
                const int prow = p * 8 + prow_l;      // pooled row 0..31
                const int y0 = prow * 2;              // staged conv-row base
#pragma unroll
                for (int seg = 0; seg < 2; ++seg) {
                    const int xl = seg * 16 + rowl;
                    bf16x8 bw[4];
#pragma unroll
                    for (int rr = 0; rr < 4; ++rr) {
                        const uint16_t* rp = &s_nhwc[((y0 + rr) * 34 + xl + kg * 2) * 4];
                        uint2 lo = *(const uint2*)rp;
                        uint2 hi = *(const uint2*)(rp + 4);
                        union { uint2 u[2]; bf16x8 v; } u;
                        u.u[0] = lo;
                        u.u[1] = hi;
                        bw[rr] = u.v;
                    }
                    f32x4 acc0[2], acc1[2];
#pragma unroll
                    for (int g = 0; g < 2; ++g)
#pragma unroll
                        for (int r = 0; r < 4; ++r) {
                            acc0[g][r] = bias[g][r];
                            acc1[g][r] = bias[g][r];
                        }
#pragma unroll
                    for (int dy = 0; dy < 3; ++dy)
#pragma unroll
                        for (int g = 0; g < 2; ++g) {
                            acc0[g] = __builtin_amdgcn_mfma_f32_16x16x32_bf16(afr[dy][g], bw[dy], acc0[g], 0, 0, 0);
                            acc1[g] = __builtin_amdgcn_mfma_f32_16x16x32_bf16(afr[dy][g], bw[dy + 1], acc1[g], 0, 0, 0);
                        }
#pragma unroll
                    for (int g = 0; g < 2; ++g)
#pragma unroll
                        for (int r = 0; r < 4; ++r) {
                            float m = fmaxf(acc0[g][r], acc1[g][r]);
                            m = fmaxf(m, 0.f);
                            float o = fmaxf(m, __shfl_xor(m, 1));
                            if (!(lane & 1)) {
                                int pcol = seg * 8 + (rowl >> 1);
                                int oc = g * 16 + kg * 4 + r;
                                s_out[(prow_l * 16 + pcol) * 32 + oc] = f2bf(o);
                            }
                        }
                }
            }
            __syncthreads();
            // store phase p: pooled rows ty*32 + p*8 .. +7 (512 uint4)
            for (int u = tid; u < 512; u += 256) {
                int px = u >> 2, c = u & 3;
                int prow = px >> 4, pcol = px & 15;
                uint4 v = *(const uint4*)&s_out[px * 32 + c * 8];
                ((uint4*)pooled1)[((((size_t)b << 12) + (ty * 32 + p * 8 + prow) * 64 + tx * 16 + pcol) << 2) + c] = v;
            }
            __syncthreads();
        }
    }
}

// ---------------------------------------------------------------------------
// Kernel C: conv2 via MFMA implicit GEMM, 16-row tile (2048 blocks).
// ---------------------------------------------------------------------------
#define S2STRIDE 36
__global__ __launch_bounds__(256) void k_conv2_mfma(const uint16_t* __restrict__ pooled1,
                                                    const uint16_t* __restrict__ wA,
                                                    const float* __restrict__ b2v,
                                                    uint16_t* __restrict__ pooled2n) {
    __shared__ uint16_t s_in[18 * 34 * S2STRIDE];  // 44064 B
    __shared__ uint16_t s_out[64 * 64];            // 8192 B
    const int bx = blockIdx.x;
    const int b = blockIdx.y;
    const int tx = bx >> 2, ty = bx & 3;
    const int X0 = tx * 32, Y0 = ty * 16;
    const int tid = threadIdx.x;

    for (int j = tid; j < 2448; j += 256) {
        int r = j / 136;
        int rem = j - r * 136;
        int px = rem >> 2, c4 = rem & 3;
        int gy = Y0 - 1 + r, gx = X0 - 1 + px;
        uint4 v = make_uint4(0, 0, 0, 0);
        if ((unsigned)gy < 64u && (unsigned)gx < 64u)
            v = ((const uint4*)pooled1)[((((size_t)b << 12) + gy * 64 + gx) << 2) + c4];
        *(uint4*)&s_in[(r * 34 + px) * S2STRIDE + c4 * 8] = v;
    }

    const int wv = tid >> 6, lane = tid & 63;
    const int ocq = wv & 1, xth = wv >> 1;
    const int rowl = lane & 15, kg = lane >> 4;

    bf16x8 afr[9][2];
#pragma unroll
    for (int t = 0; t < 9; ++t)
#pragma unroll
        for (int g = 0; g < 2; ++g)
            afr[t][g] = *(const bf16x8*)(wA + t * 2048 + (ocq * 32 + g * 16 + rowl) * 32 + kg * 8);
    float bias[2][4];
#pragma unroll
    for (int g = 0; g < 2; ++g)
#pragma unroll
        for (int r = 0; r < 4; ++r)
            bias[g][r] = b2v[ocq * 32 + g * 16 + kg * 4 + r];

    __syncthreads();

#pragma unroll
    for (int h = 0; h < 2; ++h) {
        for (int yl = 0; yl < 4; ++yl) {
            const int yp = h * 4 + yl;
            f32x4 acc[2][2];
#pragma unroll
            for (int p = 0; p < 2; ++p)
#pragma unroll
                for (int g = 0; g < 2; ++g)
#pragma unroll
                    for (int r = 0; r < 4; ++r) acc[p][g][r] = bias[g][r];

            bf16x8 bfr[4][3];
#pragma unroll
            for (int rr = 0; rr < 4; ++rr)
#pragma unroll
                for (int dx = 0; dx < 3; ++dx) {
                    int pix = (2 * yp + rr) * 34 + xth * 16 + rowl + dx;
                    bfr[rr][dx] = *(const bf16x8*)(s_in + pix * S2STRIDE + kg * 8);
                }
#pragma unroll
            for (int dy = 0; dy < 3; ++dy)
#pragma unroll
                for (int dx = 0; dx < 3; ++dx) {
                    int t = dy * 3 + dx;
#pragma unroll
                    for (int g = 0; g < 2; ++g) {
                        acc[0][g] = __builtin_amdgcn_mfma_f32_16x16x32_bf16(afr[t][g], bfr[dy][dx], acc[0][g], 0, 0, 0);
                        acc[1][g] = __builtin_amdgcn_mfma_f32_16x16x32_bf16(afr[t][g], bfr[dy + 1][dx], acc[1][g], 0, 0, 0);
                    }
                }
#pragma unroll
            for (int g = 0; g < 2; ++g)
#pragma unroll
                for (int r = 0; r < 4; ++r) {
                    float m = fmaxf(acc[0][g][r], acc[1][g][r]);
                    m = fmaxf(m, 0.f);
                    float o = fmaxf(m, __shfl_xor(m, 1));
                    if (!(lane & 1)) {
                        int oc = ocq * 32 + g * 16 + kg * 4 + r;
                        int pxl = xth * 8 + (rowl >> 1);
                        int pl = yl * 16 + pxl;
                        s_out[pl * 64 + (oc ^ ((pxl & 7) << 3))] = f2bf(o);
                    }
                }
        }
        __syncthreads();
        const int PY0 = ty * 8 + h * 4, PX0 = tx * 16;
        for (int u = tid; u < 512; u += 256) {
            int pl = u >> 3, c = u & 7;
            int py = pl >> 4, pxl = pl & 15;
            uint4 v = *(const uint4*)&s_out[pl * 64 + ((c ^ (pxl & 7)) << 3)];
            *(uint4*)&pooled2n[((((size_t)b << 10) + (PY0 + py) * 32 + PX0 + pxl) << 6) + c * 8] = v;
        }
        __syncthreads();
    }
}

// ---------------------------------------------------------------------------
// k_mid: attn_gemm (blocks 0..1023) + prep_wfc transpose (blocks 1024..1423).
// ---------------------------------------------------------------------------
__global__ __launch_bounds__(256) void k_mid(const uint16_t* __restrict__ pooled2n,
                                             const uint16_t* __restrict__ waP,
                                             const float* __restrict__ ba,
                                             float* __restrict__ attn,
                                             const float* __restrict__ Wfc,
                                             uint16_t* __restrict__ wfcb) {
    __shared__ __align__(16) uint8_t smem[62720];
    const int bid = blockIdx.x;
    const int tid = threadIdx.x;

    if (bid < 1024) {
        uint16_t* P = (uint16_t*)smem;  // [448][70]
        const int qt = bid & 3;
        const int b = bid >> 2;
        const int R0 = qt * 8;
        const int wv = tid >> 6, lane = tid & 63;
        const int rowl = lane & 15, kg = lane >> 4;

        bf16x8 afr[4][2];
#pragma unroll
        for (int c = 0; c < 4; ++c)
#pragma unroll
            for (int ks = 0; ks < 2; ++ks)
                afr[c][ks] = *(const bf16x8*)(waP + ((c * 2 + ks) * 16 + rowl) * 32 + kg * 8);

        for (int nt = wv; nt < 28; nt += 4) {
            int hpx = nt * 16 + rowl;
            int hrow = hpx >> 5, hcol = hpx & 31;
            int gy = R0 - 3 + hrow;
            bf16x8 bf0, bf1;
            if ((unsigned)gy < 32u) {
                const uint16_t* src = pooled2n + ((((size_t)b << 10) + (gy << 5) + hcol) << 6);
                bf0 = *(const bf16x8*)(src + kg * 8);
                bf1 = *(const bf16x8*)(src + 32 + kg * 8);
            } else {
                union { uint4 u; bf16x8 v; } z;
                z.u = make_uint4(0, 0, 0, 0);
                bf0 = z.v;
                bf1 = z.v;
            }
            f32x4 acc[4];
#pragma unroll
            for (int c = 0; c < 4; ++c)
#pragma unroll
                for (int r = 0; r < 4; ++r) acc[c][r] = 0.f;
#pragma unroll
            for (int c = 0; c < 4; ++c) {
                acc[c] = __builtin_amdgcn_mfma_f32_16x16x32_bf16(afr[c][0], bf0, acc[c], 0, 0, 0);
                acc[c] = __builtin_amdgcn_mfma_f32_16x16x32_bf16(afr[c][1], bf1, acc[c], 0, 0, 0);
            }
#pragma unroll
            for (int c = 0; c < 4; ++c) {
                uint32_t lo = (uint32_t)f2bf(acc[c][0]) | ((uint32_t)f2bf(acc[c][1]) << 16);
                uint32_t hi = (uint32_t)f2bf(acc[c][2]) | ((uint32_t)f2bf(acc[c][3]) << 16);
                uint16_t* dst = &P[hpx * 70 + c * 16 + kg * 4];
                *(uint32_t*)dst = lo;
                *(uint32_t*)(dst + 2) = hi;
            }
        }
        __syncthreads();

        const int pyl = tid >> 5, px = tid & 31;
        float v = ba[0];
#pragma unroll
        for (int dy = 0; dy < 7; ++dy) {
            int hl = pyl + dy;
#pragma unroll
            for (int dx = 0; dx < 7; ++dx) {
                int qx = px + dx - 3;
                if ((unsigned)qx < 32u) v += bf2f(P[(hl * 32 + qx) * 70 + dy * 7 + dx]);
            }
        }
        attn[((size_t)b << 10) + qt * 256 + tid] = 1.f / (1.f + __expf(-v));
        return;
    }

    // ---------------- Wfc transpose-convert ----------------
    {
        uint16_t(*sT)[132] = (uint16_t(*)[132])smem;  // [64][132]
        int j0 = bid - 1024;
        int o = j0 >> 3;        // 0..49
        int px0 = (j0 & 7) * 128;
#pragma unroll
        for (int p = 0; p < 8; ++p) {
            int idx = p * 256 + tid;
            int ch = idx >> 5, c4 = idx & 31;
            float4 v = *(const float4*)&Wfc[(size_t)o * 65536 + ch * 1024 + px0 + c4 * 4];
            ushort4 u;
            u.x = f2bf(v.x);
            u.y = f2bf(v.y);
            u.z = f2bf(v.z);
            u.w = f2bf(v.w);
            *(ushort4*)&sT[ch][c4 * 4] = u;
        }
        __syncthreads();
#pragma unroll
        for (int p = 0; p < 8; ++p) {
            int idx = p * 256 + tid;
            int pxl = idx >> 4, c = idx & 15;
            ushort4 u;
            u.x = sT[4 * c + 0][pxl];
            u.y = sT[4 * c + 1][pxl];
            u.z = sT[4 * c + 2][pxl];
            u.w = sT[4 * c + 3][pxl];
            *(ushort4*)&wfcb[(size_t)o * 65536 + (size_t)(px0 + pxl) * 64 + c * 4] = u;
        }
    }
}

// ---------------------------------------------------------------------------
// Kernel D2: FC via MFMA, NHWC k-order. 1D grid of 1024: wg = it*64 + kc.
// ---------------------------------------------------------------------------
__global__ __launch_bounds__(256) void k_fc_mfma(const uint16_t* __restrict__ pooled2n,
                                                 const float* __restrict__ attn,
                                                 const uint16_t* __restrict__ wfcb,
                                                 float* __restrict__ partial) {
    __shared__ uint16_t xh[128 * 128];  // 32 KB
    const int wg = blockIdx.x;
    const int it = wg >> 6;      // 0..15
    const int kc = wg & 63;      // 0..63
    const int b0 = it * 16;
    const int K0 = kc * 1024;
    const int tid = threadIdx.x;

    for (int j = tid; j < 2048; j += 256) {
        int im = j >> 7, k8 = j & 127;
        int bimg = b0 + im;
        int gk = K0 + k8 * 8;
        int px = gk >> 6, ch0 = gk & 63;
        uint4 pv = *(const uint4*)&pooled2n[((((size_t)bimg << 10) + px) << 6) + ch0];
        float a = attn[((size_t)bimg << 10) + px];
        uint16_t s[8];
        *(uint4*)s = pv;
        uint16_t d[8];
#pragma unroll
        for (int i = 0; i < 8; ++i) d[i] = f2bf(bf2f(s[i]) * a);
        *(uint4*)&xh[k8 * 128 + im * 8] = *(uint4*)d;
    }

    const int wv = tid >> 6, lane = tid & 63;
    const int rowl = lane & 15, kg = lane >> 4;
    const uint16_t* wbase = wfcb + (size_t)(wv * 16 + rowl) * 65536 + K0 + kg * 8;

    __syncthreads();

    f32x4 acc = {0.f, 0.f, 0.f, 0.f};
#pragma unroll 4
    for (int kk = 0; kk < 32; ++kk) {
        bf16x8 af = *(const bf16x8*)(wbase + kk * 32);
        bf16x8 bf = *(const bf16x8*)&xh[(kk * 4 + kg) * 128 + rowl * 8];
        acc = __builtin_amdgcn_mfma_f32_16x16x32_bf16(af, bf, acc, 0, 0, 0);
    }
    float* pp = &partial[(((size_t)kc * 256 + (b0 + rowl)) << 6) + wv * 16 + kg * 4];
    *(f32x4*)pp = acc;
}

// ---------------------------------------------------------------------------
// Kernel E: MLP head + fusion. One wave per image.
// ---------------------------------------------------------------------------
__global__ __launch_bounds__(64) void k_head(const float* __restrict__ fbuf,
                                             const float* __restrict__ partial,
                                             const float* __restrict__ Wh1, const float* __restrict__ bh1,
                                             const float* __restrict__ Wh2, const float* __restrict__ bh2,
                                             const float* __restrict__ Wh3, const float* __restrict__ bh3,
                                             const float* __restrict__ bfc,
                                             const float* __restrict__ Wf, const float* __restrict__ bf_,
                                             const float* __restrict__ Wc, const float* __restrict__ bc,
                                             float* __restrict__ out) {
    __shared__ float fl[9];
    __shared__ float h1[32];
    __shared__ float h2[64];
    __shared__ float cat[100];
    int b = blockIdx.x;
    int l = threadIdx.x;
    if (l < 9) fl[l] = fbuf[b * 16 + l];
    __syncthreads();
    if (l < 32) {
        float a = bh1[l];
        for (int i = 0; i < 9; ++i) a += fl[i] * Wh1[l * 9 + i];
        h1[l] = fmaxf(a, 0.f);
    }
    __syncthreads();
    {
        float a = bh2[l];
        for (int i = 0; i < 32; ++i) a += h1[i] * Wh2[l * 32 + i];
        h2[l] = fmaxf(a, 0.f);
    }
    __syncthreads();
    if (l < 50) {
        float a = bh3[l];
        for (int i = 0; i < 64; ++i) a += h2[i] * Wh3[l * 64 + i];
        cat[50 + l] = fmaxf(a, 0.f);
        float s = bfc[l];
        for (int kc2 = 0; kc2 < 64; ++kc2) s += partial[(((size_t)kc2 * 256 + b) << 6) + l];
        cat[l] = fmaxf(s, 0.f);
    }
    __syncthreads();
    float a = bf_[l];
    for (int i = 0; i < 100; ++i) a += cat[i] * Wf[l * 100 + i];
    a = fmaxf(a, 0.f);
    float v = a * Wc[l];
    for (int off = 32; off; off >>= 1) v += __shfl_down(v, off);
    if (l == 0) out[b] = 1.f / (1.f + __expf(-(v + bc[0])));
}

// ---------------------------------------------------------------------------
extern "C" void kernel_launch(void* const* d_in, const int* in_sizes, int n_in,
                              void* d_out, int out_size, void* d_ws, size_t ws_size,
                              hipStream_t stream) {
    const float* images = (const float*)d_in[0];
    const float* W1 = (const float*)d_in[1];
    const float* b1 = (const float*)d_in[2];
    const float* W2 = (const float*)d_in[3];
    const float* b2 = (const float*)d_in[4];
    const float* Wa = (const float*)d_in[5];
    const float* ba = (const float*)d_in[6];
    const float* Wfc = (const float*)d_in[7];
    const float* bfc = (const float*)d_in[8];
    const float* Wh1 = (const float*)d_in[9];
    const float* bh1 = (const float*)d_in[10];
    const float* Wh2 = (const float*)d_in[11];
    const float* bh2 = (const float*)d_in[12];
    const float* Wh3 = (const float*)d_in[13];
    const float* bh3 = (const float*)d_in[14];
    const float* Wf = (const float*)d_in[15];
    const float* bf_ = (const float*)d_in[16];
    const float* Wc = (const float*)d_in[17];
    const float* bc = (const float*)d_in[18];

    // workspace layout (bytes) — unchanged
    const size_t NEEDED = 102828032;
    if (ws_size < NEEDED) return;

    char* ws = (char*)d_ws;
    uint16_t* pooled1 = (uint16_t*)ws;
    uint16_t* pooled2n = (uint16_t*)(ws + 67108864);
    float* attn = (float*)(ws + 100663296);
    float* fbuf = (float*)(ws + 101711872);
    uint16_t* wA = (uint16_t*)(ws + 102776832);
    uint16_t* wA1c = (uint16_t*)(ws + 102813696);
    uint16_t* waP = (uint16_t*)(ws + 102819840);
    uint16_t* wfcb = (uint16_t*)ws;            // alias pooled1 (dead after conv2)
    float* partial = (float*)(ws + 16777216);  // alias pooled1 (dead after conv2)
    float* out = (float*)d_out;

    hipLaunchKernelGGL(k_prep_small, dim3(100), dim3(256), 0, stream, W2, W1, Wa, wA, wA1c, waP);
    hipLaunchKernelGGL(k_front, dim3(2816), dim3(256), 0, stream, images, wA1c, b1, pooled1, fbuf);
    hipLaunchKernelGGL(k_conv2_mfma, dim3(8, 256), dim3(256), 0, stream, pooled1, wA, b2, pooled2n);
    // pooled1 dead from here
    hipLaunchKernelGGL(k_mid, dim3(1424), dim3(256), 0, stream, pooled2n, waP, ba, attn, Wfc, wfcb);
    hipLaunchKernelGGL(k_fc_mfma, dim3(1024), dim3(256), 0, stream, pooled2n, attn, wfcb, partial);
    hipLaunchKernelGGL(k_head, dim3(256), dim3(64), 0, stream, fbuf, partial,
                       Wh1, bh1, Wh2, bh2, Wh3, bh3, bfc, Wf, bf_, Wc, bc, out);
}

// Round 19
// 165.800 us; speedup vs baseline: 1.0177x; 1.0177x over previous
//
#include <hip/hip_runtime.h>
#include <stdint.h>

typedef __bf16 bf16x8 __attribute__((ext_vector_type(8)));
typedef float f32x4 __attribute__((ext_vector_type(4)));

// ---------- bf16 helpers ----------
__device__ inline float bf2f(uint16_t u) {
    uint32_t x = ((uint32_t)u) << 16;
    float f;
    __builtin_memcpy(&f, &x, 4);
    return f;
}
__device__ inline uint16_t f2bf(float f) {
    uint32_t x;
    __builtin_memcpy(&x, &f, 4);
    uint32_t r = (x + 0x7FFFu + ((x >> 16) & 1u)) >> 16;
    return (uint16_t)r;
}

// ---------------------------------------------------------------------------
// Merged small weight prep (one launch). Runs BEFORE k_front (conv1 reads wA1c).
// ---------------------------------------------------------------------------
__global__ __launch_bounds__(256) void k_prep_small(const float* __restrict__ W2,
                                                    const float* __restrict__ W1,
                                                    const float* __restrict__ Wa,
                                                    uint16_t* __restrict__ wA,
                                                    uint16_t* __restrict__ wA1c,
                                                    uint16_t* __restrict__ waP) {
    int bid = blockIdx.x;
    int tid = threadIdx.x;
    if (bid < 72) {
        int j = bid * 256 + tid;
        if (j >= 18432) return;
        int t = j >> 11, rem = j & 2047, oc = rem >> 5, ic = rem & 31;
        int dy = t / 3, dx = t - dy * 3;
        wA[j] = f2bf(W2[(oc * 32 + ic) * 9 + dy * 3 + dx]);
    } else if (bid < 84) {
        int j = (bid - 72) * 256 + tid;
        if (j >= 3072) return;
        int dy = j >> 10, rem = j & 1023, oc = rem >> 5, k = rem & 31;
        int dx = k >> 2, ic = k & 3;
        uint16_t v = 0;
        if (dx < 3 && ic < 3) v = f2bf(W1[((oc * 3 + ic) * 3 + dy) * 3 + dx]);
        wA1c[j] = v;
    } else {
        int j = (bid - 84) * 256 + tid;
        if (j >= 4096) return;
        int chunk = j >> 10, ks = (j >> 9) & 1, tl = (j >> 5) & 15, ch = j & 31;
        int t = chunk * 16 + tl;
        int cg = ks * 32 + ch;
        waP[j] = (t < 49) ? f2bf(Wa[cg * 49 + t]) : (uint16_t)0;
    }
}

// ---------------------------------------------------------------------------
// k_front: handcrafted (blocks 0..767) + conv1 MFMA (blocks 768..4863).
// conv1 tile = 32x32 conv outputs (16x16 pooled), 16 tiles/image.
// Grid MUST be 768 + 16*256 = 4864 blocks.
// ---------------------------------------------------------------------------
__global__ __launch_bounds__(256) void k_front(const float* __restrict__ img,
                                               const uint16_t* __restrict__ wA1c,
                                               const float* __restrict__ b1,
                                               uint16_t* __restrict__ pooled1,
                                               float* __restrict__ f) {
    __shared__ __align__(16) uint8_t smem[25632];
    const int bid = blockIdx.x;
    const int tid = threadIdx.x;

    if (bid < 768) {
        // ---------------- handcrafted ----------------
        int c = bid >> 8, b = bid & 255;
        const float* src = img + (((size_t)(b * 3 + c)) << 14);
        uint8_t* u8 = smem;  // [128 rows][stride 132]
        float sum = 0.f, sumsq = 0.f;
        for (int it = 0; it < 16; ++it) {
            int p4 = (it << 10) + (tid << 2);
            float4 v = *(const float4*)&src[p4];
            float f0 = floorf(v.x * 255.f), f1 = floorf(v.y * 255.f);
            float f2 = floorf(v.z * 255.f), f3 = floorf(v.w * 255.f);
            uint32_t pk = (uint32_t)(int)f0 | ((uint32_t)(int)f1 << 8) |
                          ((uint32_t)(int)f2 << 16) | ((uint32_t)(int)f3 << 24);
            int r = p4 >> 7, cc = p4 & 127;
            *(uint32_t*)(u8 + r * 132 + cc) = pk;
            sum += f0 + f1 + f2 + f3;
            sumsq += f0 * f0 + f1 * f1 + f2 * f2 + f3 * f3;
        }
        __syncthreads();
        {
            int r = tid >> 1;
            int c0 = (tid & 1) << 6;
            int rm = (r == 0) ? 1 : r - 1, rp = (r == 127) ? 126 : r + 1;
            const uint8_t* Rt = u8 + rm * 132;
            const uint8_t* Rc = u8 + r * 132;
            const uint8_t* Rb = u8 + rp * 132;
            uint32_t wt = *(const uint32_t*)(Rt + c0);
            uint32_t wm = *(const uint32_t*)(Rc + c0);
            uint32_t wb = *(const uint32_t*)(Rb + c0);
            int lt, lm, lb;  // byte at col cb-1
            if (c0 == 0) {   // col -1 -> reflect-101 -> col 1
                lt = (wt >> 8) & 255; lm = (wm >> 8) & 255; lb = (wb >> 8) & 255;
            } else {
                lt = Rt[63]; lm = Rc[63]; lb = Rb[63];
            }
            float esum = 0.f;
            for (int ch = 0; ch < 16; ++ch) {
                int cb = c0 + (ch << 2);
                bool hn = (cb + 4) < 128;
                uint32_t nt = 0, nm = 0, nb = 0;
                if (hn) {
                    nt = *(const uint32_t*)(Rt + cb + 4);
                    nm = *(const uint32_t*)(Rc + cb + 4);
                    nb = *(const uint32_t*)(Rb + cb + 4);
                }
                int t[6], m[6], bo[6];
                t[0] = lt; m[0] = lm; bo[0] = lb;
#pragma unroll
                for (int i = 0; i < 4; ++i) {
                    t[i + 1] = (wt >> (8 * i)) & 255;
                    m[i + 1] = (wm >> (8 * i)) & 255;
                    bo[i + 1] = (wb >> (8 * i)) & 255;
                }
                t[5] = hn ? (int)(nt & 255) : (int)((wt >> 16) & 255);
                m[5] = hn ? (int)(nm & 255) : (int)((wm >> 16) & 255);
                bo[5] = hn ? (int)(nb & 255) : (int)((wb >> 16) & 255);
#pragma unroll
                for (int i = 0; i < 4; ++i) {
                    int gx = (t[i + 2] - t[i]) + 2 * (m[i + 2] - m[i]) + (bo[i + 2] - bo[i]);
                    int gy = (bo[i] + 2 * bo[i + 1] + bo[i + 2]) - (t[i] + 2 * t[i + 1] + t[i + 2]);
                    esum += sqrtf((float)(gx * gx + gy * gy));
                }
                lt = t[4]; lm = m[4]; lb = bo[4];
                wt = nt; wm = nm; wb = nb;
            }
            for (int off = 32; off; off >>= 1) {
                sum += __shfl_down(sum, off);
                sumsq += __shfl_down(sumsq, off);
                esum += __shfl_down(esum, off);
            }
            __syncthreads();
            float* scratch = (float*)smem;
            int w = tid >> 6;
            if ((tid & 63) == 0) {
                scratch[w * 3 + 0] = sum;
                scratch[w * 3 + 1] = sumsq;
                scratch[w * 3 + 2] = esum;
            }
            __syncthreads();
            if (tid == 0) {
                float S = 0.f, Q = 0.f, E = 0.f;
                for (int i = 0; i < 4; ++i) {
                    S += scratch[i * 3 + 0];
                    Q += scratch[i * 3 + 1];
                    E += scratch[i * 3 + 2];
                }
                const float inv = 1.0f / 16384.0f;
                float mean = S * inv;
                float var = Q * inv - mean * mean;
                f[b * 16 + c] = E * inv;
                f[b * 16 + 3 + c] = mean;
                f[b * 16 + 6 + c] = sqrtf(fmaxf(var, 0.f));
            }
        }
        return;
    }

    // ---------------- conv1 via MFMA (32x32 conv tile) ----------------
    {
        uint16_t* s_out = (uint16_t*)smem;             // 16384 B: [16x16 px][32 oc]
        uint16_t* s_nhwc = (uint16_t*)(smem + 16384);  // 9248 B: [34x34 px][4 ic]
        const int j0 = bid - 768;
        const int tile = j0 & 15;
        const int b = j0 >> 4;
        const int ty = tile >> 2, tx = tile & 3;
        const int Y0 = ty * 32, X0 = tx * 32;

        for (int j = tid; j < 1156; j += 256) {
            int r = j / 34, sc = j - r * 34;
            int gy = Y0 - 1 + r, gx = X0 - 1 + sc;
            uint16_t d[4] = {0, 0, 0, 0};
            if ((unsigned)gy < 128u && (unsigned)gx < 128u) {
                size_t base = (((size_t)b * 3) << 14) + (gy << 7) + gx;
#pragma unroll
                for (int ic = 0; ic < 3; ++ic) d[ic] = f2bf(img[base + ((size_t)ic << 14)]);
            }
            *(uint2*)&s_nhwc[j * 4] = *(uint2*)d;
        }

        const int wv = tid >> 6, lane = tid & 63;
        const int rowl = lane & 15, kg = lane >> 4;

        bf16x8 afr[3][2];
#pragma unroll
        for (int dy = 0; dy < 3; ++dy)
#pragma unroll
            for (int g = 0; g < 2; ++g)
                afr[dy][g] = *(const bf16x8*)(wA1c + dy * 1024 + (g * 16 + rowl) * 32 + kg * 8);
        float bias[2][4];
#pragma unroll
        for (int g = 0; g < 2; ++g)
#pragma unroll
            for (int r = 0; r < 4; ++r)
                bias[g][r] = b1[g * 16 + kg * 4 + r];

        __syncthreads();

#pragma unroll
        for (int pr = 0; pr < 4; ++pr) {
#pragma unroll
            for (int seg = 0; seg < 2; ++seg) {
                const int y0 = wv * 8 + pr * 2;
                const int xl = seg * 16 + rowl;
                bf16x8 bw[4];
#pragma unroll
                for (int rr = 0; rr < 4; ++rr) {
                    const uint16_t* rp = &s_nhwc[((y0 + rr) * 34 + xl + kg * 2) * 4];
                    uint2 lo = *(const uint2*)rp;
                    uint2 hi = *(const uint2*)(rp + 4);
                    union { uint2 u[2]; bf16x8 v; } u;
                    u.u[0] = lo;
                    u.u[1] = hi;
                    bw[rr] = u.v;
                }
                f32x4 acc0[2], acc1[2];
#pragma unroll
                for (int g = 0; g < 2; ++g)
#pragma unroll
                    for (int r = 0; r < 4; ++r) {
                        acc0[g][r] = bias[g][r];
                        acc1[g][r] = bias[g][r];
                    }
#pragma unroll
                for (int dy = 0; dy < 3; ++dy)
#pragma unroll
                    for (int g = 0; g < 2; ++g) {
                        acc0[g] = __builtin_amdgcn_mfma_f32_16x16x32_bf16(afr[dy][g], bw[dy], acc0[g], 0, 0, 0);
                        acc1[g] = __builtin_amdgcn_mfma_f32_16x16x32_bf16(afr[dy][g], bw[dy + 1], acc1[g], 0, 0, 0);
                    }
#pragma unroll
                for (int g = 0; g < 2; ++g)
#pragma unroll
                    for (int r = 0; r < 4; ++r) {
                        float m = fmaxf(acc0[g][r], acc1[g][r]);
                        m = fmaxf(m, 0.f);
                        float o = fmaxf(m, __shfl_xor(m, 1));
                        if (!(lane & 1)) {
                            int prow = wv * 4 + pr;
                            int pcol = seg * 8 + (rowl >> 1);
                            int oc = g * 16 + kg * 4 + r;
                            s_out[(prow * 16 + pcol) * 32 + oc] = f2bf(o);
                        }
                    }
            }
        }
        __syncthreads();
        for (int u = tid; u < 1024; u += 256) {
            int px = u >> 2, c = u & 3;
            int prow = px >> 4, pcol = px & 15;
            uint4 v = *(const uint4*)&s_out[px * 32 + c * 8];
            ((uint4*)pooled1)[((((size_t)b << 12) + (ty * 16 + prow) * 64 + tx * 16 + pcol) << 2) + c] = v;
        }
    }
}

// ---------------------------------------------------------------------------
// Kernel C: conv2 via MFMA implicit GEMM, 16-row tile (2048 blocks).
// Grid (8, B). Two epilogue half-stores keep s_out at 8 KB. Padded staging
// stride (36 u16). Output NHWC [B][1024 px][64 oc].
// ---------------------------------------------------------------------------
#define S2STRIDE 36
__global__ __launch_bounds__(256) void k_conv2_mfma(const uint16_t* __restrict__ pooled1,
                                                    const uint16_t* __restrict__ wA,
                                                    const float* __restrict__ b2v,
                                                    uint16_t* __restrict__ pooled2n) {
    __shared__ uint16_t s_in[18 * 34 * S2STRIDE];  // 44064 B
    __shared__ uint16_t s_out[64 * 64];            // 8192 B: [pixel][oc ^ swz]
    const int bx = blockIdx.x;
    const int b = blockIdx.y;
    const int tx = bx >> 2, ty = bx & 3;
    const int X0 = tx * 32, Y0 = ty * 16;
    const int tid = threadIdx.x;

    for (int j = tid; j < 2448; j += 256) {
        int r = j / 136;
        int rem = j - r * 136;
        int px = rem >> 2, c4 = rem & 3;
        int gy = Y0 - 1 + r, gx = X0 - 1 + px;
        uint4 v = make_uint4(0, 0, 0, 0);
        if ((unsigned)gy < 64u && (unsigned)gx < 64u)
            v = ((const uint4*)pooled1)[((((size_t)b << 12) + gy * 64 + gx) << 2) + c4];
        *(uint4*)&s_in[(r * 34 + px) * S2STRIDE + c4 * 8] = v;
    }

    const int wv = tid >> 6, lane = tid & 63;
    const int ocq = wv & 1, xth = wv >> 1;
    const int rowl = lane & 15, kg = lane >> 4;

    bf16x8 afr[9][2];
#pragma unroll
    for (int t = 0; t < 9; ++t)
#pragma unroll
        for (int g = 0; g < 2; ++g)
            afr[t][g] = *(const bf16x8*)(wA + t * 2048 + (ocq * 32 + g * 16 + rowl) * 32 + kg * 8);
    float bias[2][4];
#pragma unroll
    for (int g = 0; g < 2; ++g)
#pragma unroll
        for (int r = 0; r < 4; ++r)
            bias[g][r] = b2v[ocq * 32 + g * 16 + kg * 4 + r];

    __syncthreads();

#pragma unroll
    for (int h = 0; h < 2; ++h) {
        for (int yl = 0; yl < 4; ++yl) {
            const int yp = h * 4 + yl;
            f32x4 acc[2][2];
#pragma unroll
            for (int p = 0; p < 2; ++p)
#pragma unroll
                for (int g = 0; g < 2; ++g)
#pragma unroll
                    for (int r = 0; r < 4; ++r) acc[p][g][r] = bias[g][r];

            bf16x8 bfr[4][3];
#pragma unroll
            for (int rr = 0; rr < 4; ++rr)
#pragma unroll
                for (int dx = 0; dx < 3; ++dx) {
                    int pix = (2 * yp + rr) * 34 + xth * 16 + rowl + dx;
                    bfr[rr][dx] = *(const bf16x8*)(s_in + pix * S2STRIDE + kg * 8);
                }
#pragma unroll
            for (int dy = 0; dy < 3; ++dy)
#pragma unroll
                for (int dx = 0; dx < 3; ++dx) {
                    int t = dy * 3 + dx;
#pragma unroll
                    for (int g = 0; g < 2; ++g) {
                        acc[0][g] = __builtin_amdgcn_mfma_f32_16x16x32_bf16(afr[t][g], bfr[dy][dx], acc[0][g], 0, 0, 0);
                        acc[1][g] = __builtin_amdgcn_mfma_f32_16x16x32_bf16(afr[t][g], bfr[dy + 1][dx], acc[1][g], 0, 0, 0);
                    }
                }
#pragma unroll
            for (int g = 0; g < 2; ++g)
#pragma unroll
                for (int r = 0; r < 4; ++r) {
                    float m = fmaxf(acc[0][g][r], acc[1][g][r]);
                    m = fmaxf(m, 0.f);
                    float o = fmaxf(m, __shfl_xor(m, 1));
                    if (!(lane & 1)) {
                        int oc = ocq * 32 + g * 16 + kg * 4 + r;
                        int pxl = xth * 8 + (rowl >> 1);
                        int pl = yl * 16 + pxl;
                        s_out[pl * 64 + (oc ^ ((pxl & 7) << 3))] = f2bf(o);
                    }
                }
        }
        __syncthreads();
        const int PY0 = ty * 8 + h * 4, PX0 = tx * 16;
        for (int u = tid; u < 512; u += 256) {
            int pl = u >> 3, c = u & 7;
            int py = pl >> 4, pxl = pl & 15;
            uint4 v = *(const uint4*)&s_out[pl * 64 + ((c ^ (pxl & 7)) << 3)];
            *(uint4*)&pooled2n[((((size_t)b << 10) + (PY0 + py) * 32 + PX0 + pxl) << 6) + c * 8] = v;
        }
        __syncthreads();
    }
}

// ---------------------------------------------------------------------------
// k_mid: attn_gemm (blocks 0..1023) + prep_wfc transpose (blocks 1024..1423).
// ---------------------------------------------------------------------------
__global__ __launch_bounds__(256) void k_mid(const uint16_t* __restrict__ pooled2n,
                                             const uint16_t* __restrict__ waP,
                                             const float* __restrict__ ba,
                                             float* __restrict__ attn,
                                             const float* __restrict__ Wfc,
                                             uint16_t* __restrict__ wfcb) {
    __shared__ __align__(16) uint8_t smem[62720];
    const int bid = blockIdx.x;
    const int tid = threadIdx.x;

    if (bid < 1024) {
        uint16_t* P = (uint16_t*)smem;  // [448][70]
        const int qt = bid & 3;
        const int b = bid >> 2;
        const int R0 = qt * 8;
        const int wv = tid >> 6, lane = tid & 63;
        const int rowl = lane & 15, kg = lane >> 4;

        bf16x8 afr[4][2];
#pragma unroll
        for (int c = 0; c < 4; ++c)
#pragma unroll
            for (int ks = 0; ks < 2; ++ks)
                afr[c][ks] = *(const bf16x8*)(waP + ((c * 2 + ks) * 16 + rowl) * 32 + kg * 8);

        for (int nt = wv; nt < 28; nt += 4) {
            int hpx = nt * 16 + rowl;
            int hrow = hpx >> 5, hcol = hpx & 31;
            int gy = R0 - 3 + hrow;
            bf16x8 bf0, bf1;
            if ((unsigned)gy < 32u) {
                const uint16_t* src = pooled2n + ((((size_t)b << 10) + (gy << 5) + hcol) << 6);
                bf0 = *(const bf16x8*)(src + kg * 8);
                bf1 = *(const bf16x8*)(src + 32 + kg * 8);
            } else {
                union { uint4 u; bf16x8 v; } z;
                z.u = make_uint4(0, 0, 0, 0);
                bf0 = z.v;
                bf1 = z.v;
            }
            f32x4 acc[4];
#pragma unroll
            for (int c = 0; c < 4; ++c)
#pragma unroll
                for (int r = 0; r < 4; ++r) acc[c][r] = 0.f;
#pragma unroll
            for (int c = 0; c < 4; ++c) {
                acc[c] = __builtin_amdgcn_mfma_f32_16x16x32_bf16(afr[c][0], bf0, acc[c], 0, 0, 0);
                acc[c] = __builtin_amdgcn_mfma_f32_16x16x32_bf16(afr[c][1], bf1, acc[c], 0, 0, 0);
            }
#pragma unroll
            for (int c = 0; c < 4; ++c) {
                uint32_t lo = (uint32_t)f2bf(acc[c][0]) | ((uint32_t)f2bf(acc[c][1]) << 16);
                uint32_t hi = (uint32_t)f2bf(acc[c][2]) | ((uint32_t)f2bf(acc[c][3]) << 16);
                uint16_t* dst = &P[hpx * 70 + c * 16 + kg * 4];
                *(uint32_t*)dst = lo;
                *(uint32_t*)(dst + 2) = hi;
            }
        }
        __syncthreads();

        const int pyl = tid >> 5, px = tid & 31;
        float v = ba[0];
#pragma unroll
        for (int dy = 0; dy < 7; ++dy) {
            int hl = pyl + dy;
#pragma unroll
            for (int dx = 0; dx < 7; ++dx) {
                int qx = px + dx - 3;
                if ((unsigned)qx < 32u) v += bf2f(P[(hl * 32 + qx) * 70 + dy * 7 + dx]);
            }
        }
        attn[((size_t)b << 10) + qt * 256 + tid] = 1.f / (1.f + __expf(-v));
        return;
    }

    // ---------------- Wfc transpose-convert ----------------
    {
        uint16_t(*sT)[132] = (uint16_t(*)[132])smem;  // [64][132]
        int j0 = bid - 1024;
        int o = j0 >> 3;        // 0..49
        int px0 = (j0 & 7) * 128;
#pragma unroll
        for (int p = 0; p < 8; ++p) {
            int idx = p * 256 + tid;
            int ch = idx >> 5, c4 = idx & 31;
            float4 v = *(const float4*)&Wfc[(size_t)o * 65536 + ch * 1024 + px0 + c4 * 4];
            ushort4 u;
            u.x = f2bf(v.x);
            u.y = f2bf(v.y);
            u.z = f2bf(v.z);
            u.w = f2bf(v.w);
            *(ushort4*)&sT[ch][c4 * 4] = u;
        }
        __syncthreads();
#pragma unroll
        for (int p = 0; p < 8; ++p) {
            int idx = p * 256 + tid;
            int pxl = idx >> 4, c = idx & 15;
            ushort4 u;
            u.x = sT[4 * c + 0][pxl];
            u.y = sT[4 * c + 1][pxl];
            u.z = sT[4 * c + 2][pxl];
            u.w = sT[4 * c + 3][pxl];
            *(ushort4*)&wfcb[(size_t)o * 65536 + (size_t)(px0 + pxl) * 64 + c * 4] = u;
        }
    }
}

// ---------------------------------------------------------------------------
// Kernel D2: FC via MFMA, NHWC k-order. 1D grid of 1024: wg = it*64 + kc.
// ---------------------------------------------------------------------------
__global__ __launch_bounds__(256) void k_fc_mfma(const uint16_t* __restrict__ pooled2n,
                                                 const float* __restrict__ attn,
                                                 const uint16_t* __restrict__ wfcb,
                                                 float* __restrict__ partial) {
    __shared__ uint16_t xh[128 * 128];  // 32 KB
    const int wg = blockIdx.x;
    const int it = wg >> 6;      // 0..15
    const int kc = wg & 63;      // 0..63
    const int b0 = it * 16;
    const int K0 = kc * 1024;
    const int tid = threadIdx.x;

    for (int j = tid; j < 2048; j += 256) {
        int im = j >> 7, k8 = j & 127;
        int bimg = b0 + im;
        int gk = K0 + k8 * 8;
        int px = gk >> 6, ch0 = gk & 63;
        uint4 pv = *(const uint4*)&pooled2n[((((size_t)bimg << 10) + px) << 6) + ch0];
        float a = attn[((size_t)bimg << 10) + px];
        uint16_t s[8];
        *(uint4*)s = pv;
        uint16_t d[8];
#pragma unroll
        for (int i = 0; i < 8; ++i) d[i] = f2bf(bf2f(s[i]) * a);
        *(uint4*)&xh[k8 * 128 + im * 8] = *(uint4*)d;
    }

    const int wv = tid >> 6, lane = tid & 63;
    const int rowl = lane & 15, kg = lane >> 4;
    const uint16_t* wbase = wfcb + (size_t)(wv * 16 + rowl) * 65536 + K0 + kg * 8;

    __syncthreads();

    f32x4 acc = {0.f, 0.f, 0.f, 0.f};
#pragma unroll 4
    for (int kk = 0; kk < 32; ++kk) {
        bf16x8 af = *(const bf16x8*)(wbase + kk * 32);
        bf16x8 bf = *(const bf16x8*)&xh[(kk * 4 + kg) * 128 + rowl * 8];
        acc = __builtin_amdgcn_mfma_f32_16x16x32_bf16(af, bf, acc, 0, 0, 0);
    }
    float* pp = &partial[(((size_t)kc * 256 + (b0 + rowl)) << 6) + wv * 16 + kg * 4];
    *(f32x4*)pp = acc;
}

// ---------------------------------------------------------------------------
// Kernel E: MLP head + fusion. One wave per image.
// ---------------------------------------------------------------------------
__global__ __launch_bounds__(64) void k_head(const float* __restrict__ fbuf,
                                             const float* __restrict__ partial,
                                             const float* __restrict__ Wh1, const float* __restrict__ bh1,
                                             const float* __restrict__ Wh2, const float* __restrict__ bh2,
                                             const float* __restrict__ Wh3, const float* __restrict__ bh3,
                                             const float* __restrict__ bfc,
                                             const float* __restrict__ Wf, const float* __restrict__ bf_,
                                             const float* __restrict__ Wc, const float* __restrict__ bc,
                                             float* __restrict__ out) {
    __shared__ float fl[9];
    __shared__ float h1[32];
    __shared__ float h2[64];
    __shared__ float cat[100];
    int b = blockIdx.x;
    int l = threadIdx.x;
    if (l < 9) fl[l] = fbuf[b * 16 + l];
    __syncthreads();
    if (l < 32) {
        float a = bh1[l];
        for (int i = 0; i < 9; ++i) a += fl[i] * Wh1[l * 9 + i];
        h1[l] = fmaxf(a, 0.f);
    }
    __syncthreads();
    {
        float a = bh2[l];
        for (int i = 0; i < 32; ++i) a += h1[i] * Wh2[l * 32 + i];
        h2[l] = fmaxf(a, 0.f);
    }
    __syncthreads();
    if (l < 50) {
        float a = bh3[l];
        for (int i = 0; i < 64; ++i) a += h2[i] * Wh3[l * 64 + i];
        cat[50 + l] = fmaxf(a, 0.f);
        float s = bfc[l];
        for (int kc2 = 0; kc2 < 64; ++kc2) s += partial[(((size_t)kc2 * 256 + b) << 6) + l];
        cat[l] = fmaxf(s, 0.f);
    }
    __syncthreads();
    float a = bf_[l];
    for (int i = 0; i < 100; ++i) a += cat[i] * Wf[l * 100 + i];
    a = fmaxf(a, 0.f);
    float v = a * Wc[l];
    for (int off = 32; off; off >>= 1) v += __shfl_down(v, off);
    if (l == 0) out[b] = 1.f / (1.f + __expf(-(v + bc[0])));
}

// ---------------------------------------------------------------------------
extern "C" void kernel_launch(void* const* d_in, const int* in_sizes, int n_in,
                              void* d_out, int out_size, void* d_ws, size_t ws_size,
                              hipStream_t stream) {
    const float* images = (const float*)d_in[0];
    const float* W1 = (const float*)d_in[1];
    const float* b1 = (const float*)d_in[2];
    const float* W2 = (const float*)d_in[3];
    const float* b2 = (const float*)d_in[4];
    const float* Wa = (const float*)d_in[5];
    const float* ba = (const float*)d_in[6];
    const float* Wfc = (const float*)d_in[7];
    const float* bfc = (const float*)d_in[8];
    const float* Wh1 = (const float*)d_in[9];
    const float* bh1 = (const float*)d_in[10];
    const float* Wh2 = (const float*)d_in[11];
    const float* bh2 = (const float*)d_in[12];
    const float* Wh3 = (const float*)d_in[13];
    const float* bh3 = (const float*)d_in[14];
    const float* Wf = (const float*)d_in[15];
    const float* bf_ = (const float*)d_in[16];
    const float* Wc = (const float*)d_in[17];
    const float* bc = (const float*)d_in[18];

    // workspace layout (bytes)
    //   pooled1 bf16 NHWC [256,64,64,32] : 67108864   @ 0
    //     after conv2, reused as:
    //       wfcb    bf16 [50,65536] perm : 6553600    @ 0
    //       partial f32  [64,256,64]     : 4194304    @ 16777216
    //   pooled2n bf16 NHWC [256,1024,64] : 33554432   @ 67108864
    //   attn    f32  [256,1024]          : 1048576    @ 100663296
    //   fbuf    f32  [256,16]            : 16384      @ 101711872
    //   wA      bf16 [9,64,32]           : 36864      @ 102776832
    //   wA1c    bf16 [3,32,32]           : 6144       @ 102813696
    //   waP     bf16 [4,2,16,32]         : 8192       @ 102819840
    const size_t NEEDED = 102828032;
    if (ws_size < NEEDED) return;

    char* ws = (char*)d_ws;
    uint16_t* pooled1 = (uint16_t*)ws;
    uint16_t* pooled2n = (uint16_t*)(ws + 67108864);
    float* attn = (float*)(ws + 100663296);
    float* fbuf = (float*)(ws + 101711872);
    uint16_t* wA = (uint16_t*)(ws + 102776832);
    uint16_t* wA1c = (uint16_t*)(ws + 102813696);
    uint16_t* waP = (uint16_t*)(ws + 102819840);
    uint16_t* wfcb = (uint16_t*)ws;            // alias pooled1 (dead after conv2)
    float* partial = (float*)(ws + 16777216);  // alias pooled1 (dead after conv2)
    float* out = (float*)d_out;

    hipLaunchKernelGGL(k_prep_small, dim3(100), dim3(256), 0, stream, W2, W1, Wa, wA, wA1c, waP);
    hipLaunchKernelGGL(k_front, dim3(4864), dim3(256), 0, stream, images, wA1c, b1, pooled1, fbuf);
    hipLaunchKernelGGL(k_conv2_mfma, dim3(8, 256), dim3(256), 0, stream, pooled1, wA, b2, pooled2n);
    // pooled1 dead from here
    hipLaunchKernelGGL(k_mid, dim3(1424), dim3(256), 0, stream, pooled2n, waP, ba, attn, Wfc, wfcb);
    hipLaunchKernelGGL(k_fc_mfma, dim3(1024), dim3(256), 0, stream, pooled2n, attn, wfcb, partial);
    hipLaunchKernelGGL(k_head, dim3(256), dim3(64), 0, stream, fbuf, partial,
                       Wh1, bh1, Wh2, bh2, Wh3, bh3, bfc, Wf, bf_, Wc, bc, out);
}